// Round 3
// baseline (321.972 us; speedup 1.0000x reference)
//
#include <hip/hip_runtime.h>

#define Mm 160000
#define Nn 10000

typedef __attribute__((ext_vector_type(8))) short short8;
typedef __attribute__((ext_vector_type(4))) float float4v;

__device__ __forceinline__ short f2bf(float f) {
  unsigned u = __builtin_bit_cast(unsigned, f);
  u = (u + 0x7FFFu + ((u >> 16) & 1u)) >> 16;
  return (short)u;
}

// pack two fp32 -> bf16x2 (RNE), hi16(a) in low half, hi16(b) in high half
__device__ __forceinline__ unsigned pack2bf(float a, float b) {
  unsigned ua = __builtin_bit_cast(unsigned, a);
  unsigned ub = __builtin_bit_cast(unsigned, b);
  ua = ua + 0x7FFFu + ((ua >> 16) & 1u);
  ub = ub + 0x7FFFu + ((ub >> 16) & 1u);
  return __builtin_amdgcn_perm(ub, ua, 0x07060302);
}

// Wv [k=256][n=256] fp32 -> Wv_bt [n][k] bf16 (tiny, one-shot)
__global__ __launch_bounds__(256) void prep_k(const float* __restrict__ Wv,
                                              short* __restrict__ bt) {
  const int n = blockIdx.x, k = threadIdx.x;
  bt[n * 256 + k] = f2bf(Wv[k * 256 + n]);
}

// One block = 64 rows x 256 cols of v = x@Wv, K=256.
// Wave w owns head w (cols 64w..64w+63): LayerNorm fully in-wave.
// A (x tile) in double-buffered LDS; B fragments loaded per-wave from global
// (bt is 128 KB, L2-resident). Stage s+1 loads issued during stage s MFMAs.
__global__ __launch_bounds__(256, 3) void gemm_ln(const float* __restrict__ x,
                                                  const short* __restrict__ bt,
                                                  const float* __restrict__ gamma,
                                                  const float* __restrict__ beta,
                                                  float* __restrict__ out) {
  __shared__ short A[2][64][72];  // +8 pad: row stride 144 B
  const int t = threadIdx.x;
  const int m0 = blockIdx.x * 64;
  const int w = t >> 6, l = t & 63;
  const int c16 = l & 15;
  const int q8 = (l >> 4) * 8;
  const int ar = t >> 4, ak = (t & 15) * 4;

  const float* xg = x + (size_t)(m0 + ar) * 256 + ak;        // +j*4096 +k0
  const short* bg = bt + (size_t)(w * 64 + c16) * 256 + q8;  // +j*4096 +k0 +c*32

  float4v acc[4][4];
#pragma unroll
  for (int i = 0; i < 4; ++i)
#pragma unroll
    for (int j = 0; j < 4; ++j) acc[i][j] = (float4v){0.f, 0.f, 0.f, 0.f};

  float4 a_cur[4], a_nxt[4];
  short8 b_cur[8], b_nxt[8];

  // prologue: stage-0 loads
#pragma unroll
  for (int j = 0; j < 4; ++j) a_cur[j] = *(const float4*)(xg + j * 4096);
#pragma unroll
  for (int c = 0; c < 2; ++c)
#pragma unroll
    for (int j = 0; j < 4; ++j)
      b_cur[c * 4 + j] = *(const short8*)(bg + j * 4096 + c * 32);

#pragma unroll
  for (int s = 0; s < 4; ++s) {
    const int k0 = s * 64;
    // cvt + stage A[s&1]
#pragma unroll
    for (int j = 0; j < 4; ++j) {
      uint2 p;
      p.x = pack2bf(a_cur[j].x, a_cur[j].y);
      p.y = pack2bf(a_cur[j].z, a_cur[j].w);
      *(uint2*)&A[s & 1][ar + j * 16][ak] = p;
    }
    __syncthreads();
    // prefetch stage s+1 (latency overlaps MFMAs below)
    if (s < 3) {
#pragma unroll
      for (int j = 0; j < 4; ++j)
        a_nxt[j] = *(const float4*)(xg + (k0 + 64) + j * 4096);
#pragma unroll
      for (int c = 0; c < 2; ++c)
#pragma unroll
        for (int j = 0; j < 4; ++j)
          b_nxt[c * 4 + j] = *(const short8*)(bg + (k0 + 64) + j * 4096 + c * 32);
    }
    // MFMA on stage s
#pragma unroll
    for (int c = 0; c < 2; ++c) {
      short8 af[4];
#pragma unroll
      for (int i = 0; i < 4; ++i)
        af[i] = *(const short8*)&A[s & 1][i * 16 + c16][c * 32 + q8];
#pragma unroll
      for (int i = 0; i < 4; ++i)
#pragma unroll
        for (int j = 0; j < 4; ++j)
          acc[i][j] = __builtin_amdgcn_mfma_f32_16x16x32_bf16(
              af[i], b_cur[c * 4 + j], acc[i][j], 0, 0, 0);
    }
    if (s < 3) {
#pragma unroll
      for (int q = 0; q < 4; ++q) a_cur[q] = a_nxt[q];
#pragma unroll
      for (int q = 0; q < 8; ++q) b_cur[q] = b_nxt[q];
    }
  }

  // Epilogue: per-head LayerNorm + scatter to final layout.
  // C/D: col = c16, row = (l>>4)*4 + reg.
  float g[4], be[4];
#pragma unroll
  for (int j = 0; j < 4; ++j) {
    g[j] = gamma[j * 16 + c16];
    be[j] = beta[j * 16 + c16];
  }
  const int q4 = (l >> 4) * 4;
#pragma unroll
  for (int i = 0; i < 4; ++i) {
#pragma unroll
    for (int reg = 0; reg < 4; ++reg) {
      float s1 = acc[i][0][reg] + acc[i][1][reg] + acc[i][2][reg] + acc[i][3][reg];
      float s2 = acc[i][0][reg] * acc[i][0][reg] + acc[i][1][reg] * acc[i][1][reg] +
                 acc[i][2][reg] * acc[i][2][reg] + acc[i][3][reg] * acc[i][3][reg];
      s1 += __shfl_xor(s1, 1); s2 += __shfl_xor(s2, 1);
      s1 += __shfl_xor(s1, 2); s2 += __shfl_xor(s2, 2);
      s1 += __shfl_xor(s1, 4); s2 += __shfl_xor(s2, 4);
      s1 += __shfl_xor(s1, 8); s2 += __shfl_xor(s2, 8);
      const float mu = s1 * (1.f / 64.f);
      const float var = s2 * (1.f / 64.f) - mu * mu;
      const float inv = rsqrtf(var + 1e-5f);
      const int m = m0 + i * 16 + q4 + reg;
      const int b = m / Nn;
      const int n = m - b * Nn;
      const size_t obase = (size_t)(n & 15) * 2560000u +
                           (size_t)(b * 625 + (n >> 4)) * 256u + w * 64 + c16;
#pragma unroll
      for (int j = 0; j < 4; ++j)
        __builtin_nontemporal_store((acc[i][j][reg] - mu) * inv * g[j] + be[j],
                                    out + obase + j * 16);
    }
  }
}

extern "C" void kernel_launch(void* const* d_in, const int* in_sizes, int n_in,
                              void* d_out, int out_size, void* d_ws, size_t ws_size,
                              hipStream_t stream) {
  const float* x = (const float*)d_in[0];
  const float* Wv = (const float*)d_in[4];
  const float* gamma = (const float*)d_in[5];
  const float* beta = (const float*)d_in[6];
  float* out = (float*)d_out;
  short* wv_bt = (short*)d_ws;  // 256*256 bf16 = 128 KB

  prep_k<<<256, 256, 0, stream>>>(Wv, wv_bt);
  gemm_ln<<<Mm / 64, 256, 0, stream>>>(x, wv_bt, gamma, beta, out);
}